// Round 6
// baseline (1414.585 us; speedup 1.0000x reference)
//
#include <hip/hip_runtime.h>
#include <hip/hip_bf16.h>

#define NBMAX 256   // coarse buckets per direction (staged_scatter)
#define TILE  4096  // edges per staged-scatter tile
#define KPT   16    // TILE / 256
#define GMAXS 512   // bsum stride (max level-1 scan blocks per dir)
#define PERMK 8     // slices per bucket in permute
#define RB    16    // rows per block in xcd_gather

// seg(student) in [0,8): near-uniform 8-way split via magic multiply
__device__ __forceinline__ int seg8(unsigned r, unsigned mult8) {
    return (int)__umulhi(r, mult8);
}

// ---------------- A1: fine histograms for one pair (both dirs) ----------------
// even-dir bin = student row r  (hist[0 .. NS))
// odd-dir  bin = NS + c*8 + seg(r)  (hist[NS .. NS+8*NP))
__global__ __launch_bounds__(256) void hist_pair(
        const int* __restrict__ R, const int* __restrict__ C,
        int* __restrict__ hist, int nnz, int NS, unsigned mult8) {
    for (int i = blockIdx.x * 256 + threadIdx.x; i < nnz; i += gridDim.x * 256) {
        int r = R[i], c = C[i];
        atomicAdd(&hist[r], 1);
        atomicAdd(&hist[NS + c * 8 + seg8((unsigned)r, mult8)], 1);
    }
}

// ---------------- A2: hierarchical exclusive scan ----------------
__global__ __launch_bounds__(256) void scan_k1(
        const int* __restrict__ hist, int* __restrict__ binoffs,
        int* __restrict__ bsum, int NS, int NP8) {
    __shared__ int tmp[256];
    int d = blockIdx.y;
    int n = d ? NP8 : NS;
    int hbase = d ? NS : 0;
    int bbase = d ? NS + 1 : 0;
    int i = blockIdx.x * 256 + threadIdx.x;
    int v = (i < n) ? hist[hbase + i] : 0;
    tmp[threadIdx.x] = v;
    __syncthreads();
    for (int off = 1; off < 256; off <<= 1) {
        int t = (threadIdx.x >= off) ? tmp[threadIdx.x - off] : 0;
        __syncthreads();
        tmp[threadIdx.x] += t;
        __syncthreads();
    }
    if (i < n) binoffs[bbase + i] = tmp[threadIdx.x] - v;   // local exclusive
    if (threadIdx.x == 255) bsum[d * GMAXS + blockIdx.x] = tmp[255];
}

__global__ __launch_bounds__(512) void scan_k2(int* __restrict__ bsum, int nb1) {
    __shared__ int tmp[512];
    int d = blockIdx.x, tid = threadIdx.x;
    int v = (tid < nb1) ? bsum[d * GMAXS + tid] : 0;
    tmp[tid] = v;
    __syncthreads();
    for (int off = 1; off < 512; off <<= 1) {
        int t = (tid >= off) ? tmp[tid - off] : 0;
        __syncthreads();
        tmp[tid] += t;
        __syncthreads();
    }
    if (tid < nb1) bsum[d * GMAXS + tid] = tmp[tid] - v;
}

// finalize offsets; init fine cursors (aliases dead hist) and bucket cursors
__global__ __launch_bounds__(256) void scan_k3(
        int* __restrict__ binoffs, const int* __restrict__ bsum,
        int* __restrict__ fcur, int* __restrict__ bcur,
        int NS, int NP8, int nnz, int rsh_s, int rsh_p) {
    int d = blockIdx.y;
    int n = d ? NP8 : NS;
    int bbase = d ? NS + 1 : 0;
    int fbase = d ? NS : 0;
    int i = blockIdx.x * 256 + threadIdx.x;
    if (i < n) {
        int f = binoffs[bbase + i] + bsum[d * GMAXS + blockIdx.x];
        binoffs[bbase + i] = f;
        fcur[fbase + i] = f;
        if (!d) { if ((i & ((1 << rsh_s) - 1)) == 0) bcur[i >> rsh_s] = f; }
        else    { if ((i & ((8 << rsh_p) - 1)) == 0) bcur[NBMAX + (i >> (rsh_p + 3))] = f; }
    }
    if (blockIdx.x == 0 && threadIdx.x == 0) binoffs[bbase + n] = nnz;
}

// ---------------- A3: staged coalesced bucket scatter (rank-trick) ----------
// pack e.x = other | (key << 16)  (both < 65536)
__global__ __launch_bounds__(256) void staged_scatter(
        const int* __restrict__ key, const int* __restrict__ other,
        const float* __restrict__ vals, int* __restrict__ cursor,
        uint2* __restrict__ edges, int nnz, int rsh) {
    __shared__ int lhist[NBMAX], lofs[NBMAX], lbase[NBMAX];
    __shared__ uint2 stage[TILE];
    __shared__ int   sslot[TILE];
    int tid = threadIdx.x;
    int ntiles = (nnz + TILE - 1) / TILE;
    for (int tile = blockIdx.x; tile < ntiles; tile += gridDim.x) {
        int tbeg = tile * TILE;
        int n = nnz - tbeg; if (n > TILE) n = TILE;
        lhist[tid] = 0;
        __syncthreads();
        int myb[KPT], myr[KPT]; unsigned myo[KPT]; float myv[KPT];
        #pragma unroll
        for (int k = 0; k < KPT; ++k) {
            int s = k * 256 + tid;
            if (s < n) {
                int i = tbeg + s;
                int ky = key[i];
                myb[k] = ky >> rsh;
                myo[k] = (unsigned)other[i] | ((unsigned)ky << 16);
                myv[k] = vals[i];
                myr[k] = atomicAdd(&lhist[myb[k]], 1);   // rank within (tile,bucket)
            } else myb[k] = -1;
        }
        __syncthreads();
        int h = lhist[tid];
        lofs[tid] = h;
        __syncthreads();
        for (int off = 1; off < NBMAX; off <<= 1) {
            int t = (tid >= off) ? lofs[tid - off] : 0;
            __syncthreads();
            lofs[tid] += t;
            __syncthreads();
        }
        lofs[tid] -= h;
        if (h > 0) lbase[tid] = atomicAdd(&cursor[tid], h);
        __syncthreads();
        #pragma unroll
        for (int k = 0; k < KPT; ++k) {
            if (myb[k] >= 0) {
                int ls = lofs[myb[k]] + myr[k];
                stage[ls] = make_uint2(myo[k], __float_as_uint(myv[k]));
                sslot[ls] = lbase[myb[k]] + myr[k];
            }
        }
        __syncthreads();
        #pragma unroll
        for (int k = 0; k < KPT; ++k) {
            int s = k * 256 + tid;
            if (s < n) edges[sslot[s]] = stage[s];
        }
        __syncthreads();
    }
}

// ---------------- B: fine permute, XCD-aligned bucket slices ----------------
// bucket b sliced PERMK ways; all slices have blockIdx%8 == b%8 -> all
// writers of one bucket's span share an XCD L2 -> full-line assembly.
__global__ __launch_bounds__(256) void permute(
        const uint2* __restrict__ e1, uint2* __restrict__ e2,
        const int* __restrict__ binoffs, int* __restrict__ fcur,
        int odd, int nb, int nbi, int rsh, int NS, int NP8, unsigned mult8) {
    int g = blockIdx.x;
    int x = g & 7;
    int t = g >> 3;
    int bi = t % nbi;
    int k  = t / nbi;
    int b = x + 8 * bi;
    if (b >= nb) return;
    int bbase = odd ? NS + 1 : 0;
    int n = odd ? NP8 : NS;
    int fbin0 = odd ? ((b << rsh) * 8) : (b << rsh);
    int fbin1 = odd ? (((b + 1) << rsh) * 8) : ((b + 1) << rsh);
    if (fbin1 > n) fbin1 = n;
    int bs = binoffs[bbase + fbin0];
    int be = binoffs[bbase + fbin1];
    int len = be - bs;
    int per = (len + PERMK - 1) / PERMK;
    int lo = bs + k * per;
    int hi = lo + per; if (hi > be) hi = be;
    int fbase = odd ? NS : 0;
    for (int i = lo + threadIdx.x; i < hi; i += 256) {
        uint2 e = e1[i];
        int row = (int)(e.x >> 16);
        unsigned oth = e.x & 0xFFFFu;
        int bin = odd ? (row * 8 + seg8(oth, mult8)) : row;
        int slot = atomicAdd(&fcur[fbase + bin], 1);
        e2[slot] = make_uint2(oth, e.y);
    }
}

// ---------------- C-even: per-row wave gather, 8-deep pipelined -------------
__global__ __launch_bounds__(256) void row_gather(
        const int* __restrict__ offs, const uint2* __restrict__ edges,
        const float* __restrict__ x, float* __restrict__ out, int nrows) {
    int r = blockIdx.x * 4 + (threadIdx.x >> 6);
    int lane = threadIdx.x & 63;
    if (r >= nrows) return;
    int beg = offs[r], end = offs[r + 1];
    float acc = 0.f;
    for (int base = beg; base < end; base += 64) {
        int n = end - base; if (n > 64) n = 64;
        uint2 e = make_uint2(0u, 0u);
        if (lane < n) e = edges[base + lane];
        for (int jb = 0; jb < n; jb += 8) {
            float xv[8], vv[8];
            #pragma unroll
            for (int k = 0; k < 8; ++k) {
                int j = jb + k;
                int   c = __shfl((int)e.x, j);
                vv[k]   = __uint_as_float(__shfl((int)e.y, j));
                xv[k]   = x[((size_t)c << 6) + lane];
            }
            #pragma unroll
            for (int k = 0; k < 8; ++k) acc += vv[k] * xv[k];
        }
    }
    out[((size_t)r << 6) + lane] = acc;
}

// ---------------- C-odd: XCD-partitioned gather into partials ---------------
// slot = blockIdx&7 handles only students in segment `slot` (~1.6MB slice,
// L2-resident on its XCD). (row,slot) owned by exactly one wave -> no atomics.
__global__ __launch_bounds__(256) void xcd_gather(
        const int* __restrict__ offs, const uint2* __restrict__ edges,
        const float* __restrict__ x, float* __restrict__ partial, int NP) {
    int g = blockIdx.x;
    int slot = g & 7;
    int rb = g >> 3;
    int wave = threadIdx.x >> 6, lane = threadIdx.x & 63;
    int r0 = rb * RB + wave * (RB / 4);
    float* pbase = partial + (size_t)slot * NP * 64;
    for (int rr = 0; rr < RB / 4; ++rr) {
        int r = r0 + rr;
        if (r >= NP) break;
        int bin = r * 8 + slot;
        int beg = offs[bin], end = offs[bin + 1];
        float acc = 0.f;
        for (int base = beg; base < end; base += 64) {
            int n = end - base; if (n > 64) n = 64;
            uint2 e = make_uint2(0u, 0u);
            if (lane < n) e = edges[base + lane];
            for (int jb = 0; jb < n; jb += 8) {
                float xv[8], vv[8];
                #pragma unroll
                for (int k = 0; k < 8; ++k) {
                    int j = jb + k;
                    int   c = __shfl((int)e.x, j);
                    vv[k]   = __uint_as_float(__shfl((int)e.y, j));
                    xv[k]   = x[((size_t)c << 6) + lane];
                }
                #pragma unroll
                for (int k = 0; k < 8; ++k) acc += vv[k] * xv[k];
            }
        }
        pbase[((size_t)r << 6) + lane] = acc;
    }
}

__global__ __launch_bounds__(256) void reduce8(
        const float* __restrict__ partial, float* __restrict__ out, int n64) {
    int i = blockIdx.x * 256 + threadIdx.x;
    if (i < n64) {
        float s = 0.f;
        #pragma unroll
        for (int xx = 0; xx < 8; ++xx) s += partial[(size_t)xx * n64 + i];
        out[i] = s;
    }
}

// ---------------- fallback: round-1 atomic scatter ----------------
__global__ void spmm_scatter_kernel(const int* __restrict__ rows, const int* __restrict__ cols,
                                    const float* __restrict__ vals,
                                    const float* __restrict__ s_emb, const float* __restrict__ p_emb,
                                    float* __restrict__ out_s, float* __restrict__ out_p, int nnz) {
    long long t = (long long)blockIdx.x * blockDim.x + threadIdx.x;
    int e = (int)(t >> 6);
    int d = (int)(t & 63);
    if (e >= nnz) return;
    int r = rows[e];
    int c = cols[e];
    float v = vals[e];
    atomicAdd(&out_s[(size_t)r * 64 + d], v * p_emb[(size_t)c * 64 + d]);
    atomicAdd(&out_p[(size_t)c * 64 + d], v * s_emb[(size_t)r * 64 + d]);
}

// ---------------- host ----------------
extern "C" void kernel_launch(void* const* d_in, const int* in_sizes, int n_in,
                              void* d_out, int out_size, void* d_ws, size_t ws_size,
                              hipStream_t stream) {
    const float* s_emb   = (const float*)d_in[0];
    const float* p_emb   = (const float*)d_in[1];
    const int*   a_rows  = (const int*)d_in[2];
    const int*   a_cols  = (const int*)d_in[3];
    const float* a_vals  = (const float*)d_in[4];
    const int*   ia_rows = (const int*)d_in[5];
    const int*   ia_cols = (const int*)d_in[6];
    const float* ia_vals = (const float*)d_in[7];

    const int NS  = in_sizes[0] / 64;
    const int NP  = in_sizes[1] / 64;
    const int nnz = in_sizes[2];
    const int NP8 = NP * 8;

    float* out = (float*)d_out;
    float* out_sc  = out;
    float* out_sic = out_sc  + (size_t)NS * 64;
    float* out_pc  = out_sic + (size_t)NS * 64;
    float* out_pic = out_pc  + (size_t)NP * 64;

    int rsh_s = 0; while ((((long long)NS + (1LL << rsh_s) - 1) >> rsh_s) > NBMAX) rsh_s++;
    int rsh_p = 0; while ((((long long)NP + (1LL << rsh_p) - 1) >> rsh_p) > NBMAX) rsh_p++;
    int nb_s = (NS + (1 << rsh_s) - 1) >> rsh_s;
    int nb_p = (NP + (1 << rsh_p) - 1) >> rsh_p;
    unsigned mult8 = (unsigned)((8ULL << 32) / (unsigned)NS);

    int nmax = (NS > NP8) ? NS : NP8;
    int gmax1 = (nmax + 255) / 256;               // level-1 scan blocks per dir

    const size_t edges_bytes = (size_t)nnz * sizeof(uint2);
    const size_t boffs_bytes = (size_t)(NS + 1 + NP8 + 1) * sizeof(int);
    const size_t fcur_bytes  = (size_t)(NS + NP8) * sizeof(int);
    const size_t need = 2 * edges_bytes + boffs_bytes + fcur_bytes
                      + 2 * GMAXS * sizeof(int) + 2 * NBMAX * sizeof(int) + 256;
    const bool packable = (NS <= 0xFFFF) && (NP <= 0xFFFF) &&
                          (gmax1 <= GMAXS) &&
                          (edges_bytes >= (size_t)NP8 * 64 * sizeof(float));

    if (ws_size < need || !packable) {
        hipMemsetAsync(d_out, 0, (size_t)out_size * sizeof(float), stream);
        const long long total = (long long)nnz * 64;
        const int grid = (int)((total + 255) / 256);
        spmm_scatter_kernel<<<grid, 256, 0, stream>>>(a_rows, a_cols, a_vals, s_emb, p_emb,
                                                      out_sc, out_pc, nnz);
        spmm_scatter_kernel<<<grid, 256, 0, stream>>>(ia_rows, ia_cols, ia_vals, s_emb, p_emb,
                                                      out_sic, out_pic, nnz);
        return;
    }

    char* w = (char*)d_ws;
    uint2* edges1  = (uint2*)w;  w += edges_bytes;    // also partial buffers (aliased)
    uint2* edges2  = (uint2*)w;  w += edges_bytes;
    int*   binoffs = (int*)w;    w += boffs_bytes;
    int*   fcur    = (int*)w;    w += fcur_bytes;     // fine cursors (aliases hist role)
    int*   bsum    = (int*)w;    w += 2 * GMAXS * sizeof(int);
    int*   bcur    = (int*)w;
    int*   hist    = fcur;                            // hist consumed by scan, then reused

    const int ntiles = (nnz + TILE - 1) / TILE;
    const int nbi_s = (nb_s + 7) / 8, nbi_p = (nb_p + 7) / 8;
    float* partial = (float*)edges1;

    struct Pair { const int* R; const int* C; const float* V; float* oe; float* oo; };
    Pair pairs[2] = {
        { a_rows,  a_cols,  a_vals,  out_sc,  out_pc  },
        { ia_rows, ia_cols, ia_vals, out_sic, out_pic },
    };

    for (int p = 0; p < 2; ++p) {
        const Pair& P = pairs[p];
        // A: fine histograms + offsets for both dirs of this pair
        hipMemsetAsync(hist, 0, fcur_bytes, stream);
        hist_pair<<<1024, 256, 0, stream>>>(P.R, P.C, hist, nnz, NS, mult8);
        scan_k1<<<dim3(gmax1, 2), 256, 0, stream>>>(hist, binoffs, bsum, NS, NP8);
        scan_k2<<<2, 512, 0, stream>>>(bsum, gmax1);
        scan_k3<<<dim3(gmax1, 2), 256, 0, stream>>>(binoffs, bsum, fcur, bcur,
                                                    NS, NP8, nnz, rsh_s, rsh_p);
        // even dir: key = student row, x = p_emb
        staged_scatter<<<ntiles, 256, 0, stream>>>(P.R, P.C, P.V, bcur, edges1, nnz, rsh_s);
        permute<<<8 * nbi_s * PERMK, 256, 0, stream>>>(edges1, edges2, binoffs, fcur,
                                                       0, nb_s, nbi_s, rsh_s, NS, NP8, mult8);
        row_gather<<<(NS + 3) / 4, 256, 0, stream>>>(binoffs, edges2, p_emb, P.oe, NS);
        // odd dir: key = problem col, x = s_emb, XCD-partitioned
        staged_scatter<<<ntiles, 256, 0, stream>>>(P.C, P.R, P.V, bcur + NBMAX, edges1, nnz, rsh_p);
        permute<<<8 * nbi_p * PERMK, 256, 0, stream>>>(edges1, edges2, binoffs, fcur,
                                                       1, nb_p, nbi_p, rsh_p, NS, NP8, mult8);
        xcd_gather<<<8 * ((NP + RB - 1) / RB), 256, 0, stream>>>(binoffs + NS + 1, edges2,
                                                                 s_emb, partial, NP);
        reduce8<<<(NP * 64 + 255) / 256, 256, 0, stream>>>(partial, P.oo, NP * 64);
    }
}

// Round 7
// 789.464 us; speedup vs baseline: 1.7918x; 1.7918x over previous
//
#include <hip/hip_runtime.h>
#include <hip/hip_bf16.h>

#define NBMAX 256   // coarse buckets per direction
#define TILE  4096  // edges per staged-scatter tile
#define KPT   16    // TILE / 256
#define BINSMAX 512 // max fine bins per bucket in row_scatter2

// seg(student) in [0,8): near-uniform 8-way split via magic multiply
__device__ __forceinline__ int seg8(unsigned r, unsigned mult8) {
    return (int)__umulhi(r, mult8);
}

// ---------------- A1: coarse histogram, all 4 dirs (LDS-privatized) ---------
__global__ __launch_bounds__(256) void hist_all(
        const int* __restrict__ k0, const int* __restrict__ k1,
        const int* __restrict__ k2, const int* __restrict__ k3,
        int* __restrict__ gcnt4, int nnz, int rsh_s, int rsh_p) {
    __shared__ int h[NBMAX];
    int dir = blockIdx.x & 3;
    const int* key = (dir == 0) ? k0 : (dir == 1) ? k1 : (dir == 2) ? k2 : k3;
    int rsh = (dir & 1) ? rsh_p : rsh_s;
    h[threadIdx.x] = 0;
    __syncthreads();
    int ch = blockIdx.x >> 2, nch = gridDim.x >> 2;
    for (int i = ch * 256 + threadIdx.x; i < nnz; i += nch * 256)
        atomicAdd(&h[key[i] >> rsh], 1);
    __syncthreads();
    int v = h[threadIdx.x];
    if (v) atomicAdd(&gcnt4[dir * NBMAX + threadIdx.x], v);
}

// ---------------- A2: bucket offsets for all 4 dirs (4 blocks) --------------
__global__ __launch_bounds__(256) void scan_all(
        const int* __restrict__ gcnt4, int* __restrict__ boffs4,
        int* __restrict__ bcur4, int nb_s, int nb_p, int nnz,
        int* __restrict__ offsE, int* __restrict__ offsO, int NS, int NP8) {
    __shared__ int tmp[NBMAX];
    int dir = blockIdx.x, tid = threadIdx.x;
    int nb = (dir & 1) ? nb_p : nb_s;
    int v = (tid < nb) ? gcnt4[dir * NBMAX + tid] : 0;
    tmp[tid] = v;
    __syncthreads();
    for (int off = 1; off < NBMAX; off <<= 1) {
        int t = (tid >= off) ? tmp[tid - off] : 0;
        __syncthreads();
        tmp[tid] += t;
        __syncthreads();
    }
    if (tid < nb) {
        int e = tmp[tid] - v;
        boffs4[dir * (NBMAX + 1) + tid] = e;
        bcur4[dir * NBMAX + tid] = e;
    }
    if (tid == 0) boffs4[dir * (NBMAX + 1) + nb] = nnz;
    if (dir == 0 && tid == 0) { offsE[NS] = nnz; offsO[NP8] = nnz; }
}

// ---------------- A3: staged coalesced bucket scatter (rank-trick) ----------
// pack e.x = other | (lrow << 16), lrow = key & ((1<<rsh)-1)
__global__ __launch_bounds__(256) void staged_scatter(
        const int* __restrict__ key, const int* __restrict__ other,
        const float* __restrict__ vals, int* __restrict__ cursor,
        uint2* __restrict__ edges, int nnz, int rsh) {
    __shared__ int lhist[NBMAX], lofs[NBMAX], lbase[NBMAX];
    __shared__ uint2 stage[TILE];
    __shared__ int   sslot[TILE];
    int tid = threadIdx.x;
    int lmask = (1 << rsh) - 1;
    int ntiles = (nnz + TILE - 1) / TILE;
    for (int tile = blockIdx.x; tile < ntiles; tile += gridDim.x) {
        int tbeg = tile * TILE;
        int n = nnz - tbeg; if (n > TILE) n = TILE;
        lhist[tid] = 0;
        __syncthreads();
        int myb[KPT], myr[KPT]; unsigned myo[KPT]; float myv[KPT];
        #pragma unroll
        for (int k = 0; k < KPT; ++k) {
            int s = k * 256 + tid;
            if (s < n) {
                int i = tbeg + s;
                int ky = key[i];
                myb[k] = ky >> rsh;
                myo[k] = (unsigned)other[i] | ((unsigned)(ky & lmask) << 16);
                myv[k] = vals[i];
                myr[k] = atomicAdd(&lhist[myb[k]], 1);   // rank within (tile,bucket)
            } else myb[k] = -1;
        }
        __syncthreads();
        int h = lhist[tid];
        lofs[tid] = h;
        __syncthreads();
        for (int off = 1; off < NBMAX; off <<= 1) {
            int t = (tid >= off) ? lofs[tid - off] : 0;
            __syncthreads();
            lofs[tid] += t;
            __syncthreads();
        }
        lofs[tid] -= h;
        if (h > 0) lbase[tid] = atomicAdd(&cursor[tid], h);
        __syncthreads();
        #pragma unroll
        for (int k = 0; k < KPT; ++k) {
            if (myb[k] >= 0) {
                int ls = lofs[myb[k]] + myr[k];
                stage[ls] = make_uint2(myo[k], __float_as_uint(myv[k]));
                sslot[ls] = lbase[myb[k]] + myr[k];
            }
        }
        __syncthreads();
        #pragma unroll
        for (int k = 0; k < KPT; ++k) {
            int s = k * 256 + tid;
            if (s < n) edges[sslot[s]] = stage[s];
        }
        __syncthreads();
    }
}

// ---------------- B: parallel within-bucket fine sort (8 slices/bucket) -----
// grid block g: xcd slot x=g&7, slice sk=(g>>3)&7, bi=g>>6, bucket b=x+8*bi.
// All 9 passes over one bucket (8 slice blocks) share g%8 -> same XCD ->
// bucket span (~160KB) is L2-resident; zero global atomics.
// even dir: bin = lrow;  odd dir: bin = lrow*8 + seg8(other).
__global__ __launch_bounds__(512) void row_scatter2(
        const uint2* __restrict__ e1, uint2* __restrict__ e2,
        const int* __restrict__ boffs, int* __restrict__ offs,
        int odd, int nb, int rsh, int nrows, unsigned mult8) {
    __shared__ int cnt[BINSMAX * 8];
    __shared__ int tot[512];
    __shared__ int lcur[BINSMAX];
    int tid = threadIdx.x;
    int g = blockIdx.x;
    int x = g & 7;
    int sk = (g >> 3) & 7;
    int bi = g >> 6;
    int b = x + 8 * bi;
    if (b >= nb) return;
    int bins = odd ? (8 << rsh) : (1 << rsh);      // <= 512
    int beg = boffs[b], end = boffs[b + 1];
    int len = end - beg;
    for (int i = tid; i < BINSMAX * 8; i += 512) cnt[i] = 0;
    __syncthreads();
    int per = (len + 7) >> 3;
    if (len > 0) {
        for (int i = beg + tid; i < end; i += 512) {
            uint2 e = e1[i];
            int lrow = (int)(e.x >> 16);
            int bin = odd ? (lrow * 8 + seg8(e.x & 0xFFFFu, mult8)) : lrow;
            int sl = (i - beg) / per;
            atomicAdd(&cnt[bin * 8 + sl], 1);
        }
    }
    __syncthreads();
    int own = 0;
    if (tid < bins) {
        #pragma unroll
        for (int j = 0; j < 8; ++j) own += cnt[tid * 8 + j];
    }
    tot[tid] = (tid < bins) ? own : 0;
    __syncthreads();
    for (int off = 1; off < 512; off <<= 1) {
        int t = (tid >= off) ? tot[tid - off] : 0;
        __syncthreads();
        tot[tid] += t;
        __syncthreads();
    }
    if (tid < bins) {
        int fineoff = tot[tid] - own;              // exclusive within bucket
        int basej = 0;
        for (int j = 0; j < sk; ++j) basej += cnt[tid * 8 + j];
        lcur[tid] = beg + fineoff + basej;
        if (sk == 0) {                             // publish per-bin global offsets
            if (!odd) {
                int row = (b << rsh) + tid;
                if (row < nrows) offs[row] = beg + fineoff;
            } else {
                int row = (b << rsh) + (tid >> 3);
                if (row < nrows) offs[(row << 3) + (tid & 7)] = beg + fineoff;
            }
        }
    }
    __syncthreads();
    int lo = beg + sk * per;
    int hi = lo + per; if (hi > end) hi = end;
    for (int i = lo + tid; i < hi; i += 512) {
        uint2 e = e1[i];
        int lrow = (int)(e.x >> 16);
        int bin = odd ? (lrow * 8 + seg8(e.x & 0xFFFFu, mult8)) : lrow;
        int slot = atomicAdd(&lcur[bin], 1);
        e2[slot] = make_uint2(e.x & 0xFFFFu, e.y); // stores confined to bucket span (one XCD L2)
    }
}

// ---------------- C-even: per-row wave gather, 8-deep pipelined -------------
__global__ __launch_bounds__(256) void row_gather(
        const int* __restrict__ offs, const uint2* __restrict__ edges,
        const float* __restrict__ x, float* __restrict__ out, int nrows) {
    int r = blockIdx.x * 4 + (threadIdx.x >> 6);
    int lane = threadIdx.x & 63;
    if (r >= nrows) return;
    int beg = offs[r], end = offs[r + 1];
    float acc = 0.f;
    for (int base = beg; base < end; base += 64) {
        int n = end - base; if (n > 64) n = 64;
        uint2 e = make_uint2(0u, 0u);
        if (lane < n) e = edges[base + lane];
        for (int jb = 0; jb < n; jb += 8) {
            float xv[8], vv[8];
            #pragma unroll
            for (int k = 0; k < 8; ++k) {
                int j = jb + k;
                int   c = __shfl((int)e.x, j);
                vv[k]   = __uint_as_float(__shfl((int)e.y, j));
                xv[k]   = x[((size_t)c << 6) + lane];
            }
            #pragma unroll
            for (int k = 0; k < 8; ++k) acc += vv[k] * xv[k];
        }
    }
    out[((size_t)r << 6) + lane] = acc;
}

// ---------------- C-odd: XCD-partitioned gather into partials ---------------
// slot = g&7: this block only reads students in segment `slot` (~1.6MB,
// L2-resident on its XCD). (row,slot) owned by one wave -> no atomics.
__global__ __launch_bounds__(256) void xcd_gather(
        const int* __restrict__ offs, const uint2* __restrict__ edges,
        const float* __restrict__ x, float* __restrict__ partial, int NP) {
    int g = blockIdx.x;
    int slot = g & 7;
    int t = g >> 3;
    int wave = threadIdx.x >> 6, lane = threadIdx.x & 63;
    int r = t * 4 + wave;
    if (r >= NP) return;
    int bin = r * 8 + slot;
    int beg = offs[bin], end = offs[bin + 1];
    float acc = 0.f;
    for (int base = beg; base < end; base += 64) {
        int n = end - base; if (n > 64) n = 64;
        uint2 e = make_uint2(0u, 0u);
        if (lane < n) e = edges[base + lane];
        for (int jb = 0; jb < n; jb += 8) {
            float xv[8], vv[8];
            #pragma unroll
            for (int k = 0; k < 8; ++k) {
                int j = jb + k;
                int   c = __shfl((int)e.x, j);
                vv[k]   = __uint_as_float(__shfl((int)e.y, j));
                xv[k]   = x[((size_t)c << 6) + lane];
            }
            #pragma unroll
            for (int k = 0; k < 8; ++k) acc += vv[k] * xv[k];
        }
    }
    partial[(size_t)slot * NP * 64 + ((size_t)r << 6) + lane] = acc;
}

__global__ __launch_bounds__(256) void reduce8(
        const float* __restrict__ partial, float* __restrict__ out, int n64) {
    int i = blockIdx.x * 256 + threadIdx.x;
    if (i < n64) {
        float s = 0.f;
        #pragma unroll
        for (int xx = 0; xx < 8; ++xx) s += partial[(size_t)xx * n64 + i];
        out[i] = s;
    }
}

// ---------------- fallback: round-1 atomic scatter ----------------
__global__ void spmm_scatter_kernel(const int* __restrict__ rows, const int* __restrict__ cols,
                                    const float* __restrict__ vals,
                                    const float* __restrict__ s_emb, const float* __restrict__ p_emb,
                                    float* __restrict__ out_s, float* __restrict__ out_p, int nnz) {
    long long t = (long long)blockIdx.x * blockDim.x + threadIdx.x;
    int e = (int)(t >> 6);
    int d = (int)(t & 63);
    if (e >= nnz) return;
    int r = rows[e];
    int c = cols[e];
    float v = vals[e];
    atomicAdd(&out_s[(size_t)r * 64 + d], v * p_emb[(size_t)c * 64 + d]);
    atomicAdd(&out_p[(size_t)c * 64 + d], v * s_emb[(size_t)r * 64 + d]);
}

// ---------------- host ----------------
extern "C" void kernel_launch(void* const* d_in, const int* in_sizes, int n_in,
                              void* d_out, int out_size, void* d_ws, size_t ws_size,
                              hipStream_t stream) {
    const float* s_emb   = (const float*)d_in[0];
    const float* p_emb   = (const float*)d_in[1];
    const int*   a_rows  = (const int*)d_in[2];
    const int*   a_cols  = (const int*)d_in[3];
    const float* a_vals  = (const float*)d_in[4];
    const int*   ia_rows = (const int*)d_in[5];
    const int*   ia_cols = (const int*)d_in[6];
    const float* ia_vals = (const float*)d_in[7];

    const int NS  = in_sizes[0] / 64;
    const int NP  = in_sizes[1] / 64;
    const int nnz = in_sizes[2];
    const int NP8 = NP * 8;

    float* out = (float*)d_out;
    float* out_sc  = out;
    float* out_sic = out_sc  + (size_t)NS * 64;
    float* out_pc  = out_sic + (size_t)NS * 64;
    float* out_pic = out_pc  + (size_t)NP * 64;

    int rsh_s = 0; while ((((long long)NS + (1LL << rsh_s) - 1) >> rsh_s) > NBMAX) rsh_s++;
    int rsh_p = 0; while ((((long long)NP + (1LL << rsh_p) - 1) >> rsh_p) > NBMAX) rsh_p++;
    int nb_s = (NS + (1 << rsh_s) - 1) >> rsh_s;
    int nb_p = (NP + (1 << rsh_p) - 1) >> rsh_p;
    unsigned mult8 = (unsigned)((8ULL << 32) / (unsigned)NS);

    const size_t edges_bytes = (size_t)nnz * sizeof(uint2);
    const size_t offsE_bytes = (size_t)(NS + 1) * sizeof(int);
    const size_t offsO_bytes = (size_t)(NP8 + 1) * sizeof(int);
    const size_t need = 2 * edges_bytes + offsE_bytes + offsO_bytes
                      + (size_t)(4 * NBMAX + 4 * (NBMAX + 1) + 4 * NBMAX) * sizeof(int) + 256;
    const bool packable = (NS <= 0xFFFF) && (NP <= 0xFFFF) &&
                          ((1 << rsh_s) <= BINSMAX) && ((8 << rsh_p) <= BINSMAX) &&
                          (edges_bytes >= (size_t)NP8 * 64 * sizeof(float));

    if (ws_size < need || !packable) {
        hipMemsetAsync(d_out, 0, (size_t)out_size * sizeof(float), stream);
        const long long total = (long long)nnz * 64;
        const int grid = (int)((total + 255) / 256);
        spmm_scatter_kernel<<<grid, 256, 0, stream>>>(a_rows, a_cols, a_vals, s_emb, p_emb,
                                                      out_sc, out_pc, nnz);
        spmm_scatter_kernel<<<grid, 256, 0, stream>>>(ia_rows, ia_cols, ia_vals, s_emb, p_emb,
                                                      out_sic, out_pic, nnz);
        return;
    }

    char* w = (char*)d_ws;
    uint2* edges1 = (uint2*)w;  w += edges_bytes;     // aliased as `partial` in odd gathers
    uint2* edges2 = (uint2*)w;  w += edges_bytes;
    int*   offsE  = (int*)w;    w += offsE_bytes;
    int*   offsO  = (int*)w;    w += offsO_bytes;
    int*   gcnt4  = (int*)w;    w += 4 * NBMAX * sizeof(int);
    int*   boffs4 = (int*)w;    w += 4 * (NBMAX + 1) * sizeof(int);
    int*   bcur4  = (int*)w;
    float* partial = (float*)edges1;

    hipMemsetAsync(gcnt4, 0, 4 * NBMAX * sizeof(int), stream);
    // dirs: 0 = a by row, 1 = a by col, 2 = ia by row, 3 = ia by col
    hist_all<<<1024, 256, 0, stream>>>(a_rows, a_cols, ia_rows, ia_cols,
                                       gcnt4, nnz, rsh_s, rsh_p);
    scan_all<<<4, 256, 0, stream>>>(gcnt4, boffs4, bcur4, nb_s, nb_p, nnz,
                                    offsE, offsO, NS, NP8);

    const int ntiles = (nnz + TILE - 1) / TILE;
    const int grid_rs_s = 64 * ((nb_s + 7) / 8);
    const int grid_rs_p = 64 * ((nb_p + 7) / 8);

    struct Dir { const int* key; const int* other; const float* vals;
                 float* out; int odd; };
    // output order: (student_c, student_ic, problem_c, problem_ic)
    Dir dirs[4] = {
        { a_rows,  a_cols,  a_vals,  out_sc,  0 },
        { a_cols,  a_rows,  a_vals,  out_pc,  1 },
        { ia_rows, ia_cols, ia_vals, out_sic, 0 },
        { ia_cols, ia_rows, ia_vals, out_pic, 1 },
    };
    int hd[4] = { 0, 1, 2, 3 };
    for (int t = 0; t < 4; ++t) {
        const Dir& D = dirs[t];
        int d = hd[t];
        if (!D.odd) {
            staged_scatter<<<ntiles, 256, 0, stream>>>(D.key, D.other, D.vals,
                                                       bcur4 + d * NBMAX, edges1, nnz, rsh_s);
            row_scatter2<<<grid_rs_s, 512, 0, stream>>>(edges1, edges2,
                                                        boffs4 + d * (NBMAX + 1), offsE,
                                                        0, nb_s, rsh_s, NS, mult8);
            row_gather<<<(NS + 3) / 4, 256, 0, stream>>>(offsE, edges2, p_emb, D.out, NS);
        } else {
            staged_scatter<<<ntiles, 256, 0, stream>>>(D.key, D.other, D.vals,
                                                       bcur4 + d * NBMAX, edges1, nnz, rsh_p);
            row_scatter2<<<grid_rs_p, 512, 0, stream>>>(edges1, edges2,
                                                        boffs4 + d * (NBMAX + 1), offsO,
                                                        1, nb_p, rsh_p, NP, mult8);
            xcd_gather<<<8 * ((NP + 3) / 4), 256, 0, stream>>>(offsO, edges2,
                                                               s_emb, partial, NP);
            reduce8<<<(NP * 64 + 255) / 256, 256, 0, stream>>>(partial, D.out, NP * 64);
        }
    }
}

// Round 8
// 646.632 us; speedup vs baseline: 2.1876x; 1.2209x over previous
//
#include <hip/hip_runtime.h>
#include <hip/hip_bf16.h>

#define NBMAX 256   // coarse buckets per direction
#define TILE  4096  // edges per staged-scatter tile
#define KPT   16    // TILE / 256
#define BINSMAX 512 // max fine bins per bucket in row_scatter2

// seg(student) in [0,8): near-uniform 8-way split via magic multiply
__device__ __forceinline__ int seg8(unsigned r, unsigned mult8) {
    return (int)__umulhi(r, mult8);
}

// ---------------- A1: coarse histogram, all 4 dirs (LDS-privatized) ---------
__global__ __launch_bounds__(256) void hist_all(
        const int* __restrict__ k0, const int* __restrict__ k1,
        const int* __restrict__ k2, const int* __restrict__ k3,
        int* __restrict__ gcnt4, int nnz, int rsh_s, int rsh_p) {
    __shared__ int h[NBMAX];
    int dir = blockIdx.x & 3;
    const int* key = (dir == 0) ? k0 : (dir == 1) ? k1 : (dir == 2) ? k2 : k3;
    int rsh = (dir & 1) ? rsh_p : rsh_s;
    h[threadIdx.x] = 0;
    __syncthreads();
    int ch = blockIdx.x >> 2, nch = gridDim.x >> 2;
    for (int i = ch * 256 + threadIdx.x; i < nnz; i += nch * 256)
        atomicAdd(&h[key[i] >> rsh], 1);
    __syncthreads();
    int v = h[threadIdx.x];
    if (v) atomicAdd(&gcnt4[dir * NBMAX + threadIdx.x], v);
}

// ---------------- A2: bucket offsets for all 4 dirs (4 blocks) --------------
__global__ __launch_bounds__(256) void scan_all(
        const int* __restrict__ gcnt4, int* __restrict__ boffs4,
        int* __restrict__ bcur4, int nb_s, int nb_p, int nnz,
        int* __restrict__ offsE, int* __restrict__ offsO, int NS, int NP8) {
    __shared__ int tmp[NBMAX];
    int dir = blockIdx.x, tid = threadIdx.x;
    int nb = (dir & 1) ? nb_p : nb_s;
    int v = (tid < nb) ? gcnt4[dir * NBMAX + tid] : 0;
    tmp[tid] = v;
    __syncthreads();
    for (int off = 1; off < NBMAX; off <<= 1) {
        int t = (tid >= off) ? tmp[tid - off] : 0;
        __syncthreads();
        tmp[tid] += t;
        __syncthreads();
    }
    if (tid < nb) {
        int e = tmp[tid] - v;
        boffs4[dir * (NBMAX + 1) + tid] = e;
        bcur4[dir * NBMAX + tid] = e;
    }
    if (tid == 0) boffs4[dir * (NBMAX + 1) + nb] = nnz;
    if (dir == 0 && tid == 0) { offsE[NS] = nnz; offsO[NP8] = nnz; }
}

// ---------------- A3: staged coalesced bucket scatter (rank-trick) ----------
// pack e.x = other | (lrow << 16), lrow = key & ((1<<rsh)-1)
__global__ __launch_bounds__(256) void staged_scatter(
        const int* __restrict__ key, const int* __restrict__ other,
        const float* __restrict__ vals, int* __restrict__ cursor,
        uint2* __restrict__ edges, int nnz, int rsh) {
    __shared__ int lhist[NBMAX], lofs[NBMAX], lbase[NBMAX];
    __shared__ uint2 stage[TILE];
    __shared__ int   sslot[TILE];
    int tid = threadIdx.x;
    int lmask = (1 << rsh) - 1;
    int ntiles = (nnz + TILE - 1) / TILE;
    for (int tile = blockIdx.x; tile < ntiles; tile += gridDim.x) {
        int tbeg = tile * TILE;
        int n = nnz - tbeg; if (n > TILE) n = TILE;
        lhist[tid] = 0;
        __syncthreads();
        int myb[KPT], myr[KPT]; unsigned myo[KPT]; float myv[KPT];
        #pragma unroll
        for (int k = 0; k < KPT; ++k) {
            int s = k * 256 + tid;
            if (s < n) {
                int i = tbeg + s;
                int ky = key[i];
                myb[k] = ky >> rsh;
                myo[k] = (unsigned)other[i] | ((unsigned)(ky & lmask) << 16);
                myv[k] = vals[i];
                myr[k] = atomicAdd(&lhist[myb[k]], 1);   // rank within (tile,bucket)
            } else myb[k] = -1;
        }
        __syncthreads();
        int h = lhist[tid];
        lofs[tid] = h;
        __syncthreads();
        for (int off = 1; off < NBMAX; off <<= 1) {
            int t = (tid >= off) ? lofs[tid - off] : 0;
            __syncthreads();
            lofs[tid] += t;
            __syncthreads();
        }
        lofs[tid] -= h;
        if (h > 0) lbase[tid] = atomicAdd(&cursor[tid], h);
        __syncthreads();
        #pragma unroll
        for (int k = 0; k < KPT; ++k) {
            if (myb[k] >= 0) {
                int ls = lofs[myb[k]] + myr[k];
                stage[ls] = make_uint2(myo[k], __float_as_uint(myv[k]));
                sslot[ls] = lbase[myb[k]] + myr[k];
            }
        }
        __syncthreads();
        #pragma unroll
        for (int k = 0; k < KPT; ++k) {
            int s = k * 256 + tid;
            if (s < n) edges[sslot[s]] = stage[s];
        }
        __syncthreads();
    }
}

// ---------------- B: parallel within-bucket fine sort (8 slices/bucket) -----
__global__ __launch_bounds__(512) void row_scatter2(
        const uint2* __restrict__ e1, uint2* __restrict__ e2,
        const int* __restrict__ boffs, int* __restrict__ offs,
        int odd, int nb, int rsh, int nrows, unsigned mult8) {
    __shared__ int cnt[BINSMAX * 8];
    __shared__ int tot[512];
    __shared__ int lcur[BINSMAX];
    int tid = threadIdx.x;
    int g = blockIdx.x;
    int x = g & 7;
    int sk = (g >> 3) & 7;
    int bi = g >> 6;
    int b = x + 8 * bi;
    if (b >= nb) return;
    int bins = odd ? (8 << rsh) : (1 << rsh);      // <= 512
    int beg = boffs[b], end = boffs[b + 1];
    int len = end - beg;
    for (int i = tid; i < BINSMAX * 8; i += 512) cnt[i] = 0;
    __syncthreads();
    int per = (len + 7) >> 3;
    if (len > 0) {
        for (int i = beg + tid; i < end; i += 512) {
            uint2 e = e1[i];
            int lrow = (int)(e.x >> 16);
            int bin = odd ? (lrow * 8 + seg8(e.x & 0xFFFFu, mult8)) : lrow;
            int sl = (i - beg) / per;
            atomicAdd(&cnt[bin * 8 + sl], 1);
        }
    }
    __syncthreads();
    int own = 0;
    if (tid < bins) {
        #pragma unroll
        for (int j = 0; j < 8; ++j) own += cnt[tid * 8 + j];
    }
    tot[tid] = (tid < bins) ? own : 0;
    __syncthreads();
    for (int off = 1; off < 512; off <<= 1) {
        int t = (tid >= off) ? tot[tid - off] : 0;
        __syncthreads();
        tot[tid] += t;
        __syncthreads();
    }
    if (tid < bins) {
        int fineoff = tot[tid] - own;              // exclusive within bucket
        int basej = 0;
        for (int j = 0; j < sk; ++j) basej += cnt[tid * 8 + j];
        lcur[tid] = beg + fineoff + basej;
        if (sk == 0) {
            if (!odd) {
                int row = (b << rsh) + tid;
                if (row < nrows) offs[row] = beg + fineoff;
            } else {
                int row = (b << rsh) + (tid >> 3);
                if (row < nrows) offs[(row << 3) + (tid & 7)] = beg + fineoff;
            }
        }
    }
    __syncthreads();
    int lo = beg + sk * per;
    int hi = lo + per; if (hi > end) hi = end;
    for (int i = lo + tid; i < hi; i += 512) {
        uint2 e = e1[i];
        int lrow = (int)(e.x >> 16);
        int bin = odd ? (lrow * 8 + seg8(e.x & 0xFFFFu, mult8)) : lrow;
        int slot = atomicAdd(&lcur[bin], 1);
        e2[slot] = make_uint2(e.x & 0xFFFFu, e.y);
    }
}

// ---------------- gather core: 4 edges/step, float4 per lane ----------------
// lane = (q = lane>>4 edge subgroup, l16 = lane&15 dim quad).
// One dwordx4 VMEM instr covers 4 edges; 2 bpermutes per 4 edges.
// Zero-filled tail lanes give v=0 -> exact-zero contribution.
__device__ __forceinline__ float4 gather_row4(
        int beg, int end, const uint2* __restrict__ edges,
        const float* __restrict__ x, int lane) {
    int q = lane >> 4, l16 = lane & 15;
    float4 acc = make_float4(0.f, 0.f, 0.f, 0.f);
    for (int base = beg; base < end; base += 64) {
        int n = end - base; if (n > 64) n = 64;
        uint2 e = make_uint2(0u, 0u);
        if (lane < n) e = edges[base + lane];
        for (int j = 0; j < n; j += 8) {
            int i0 = j + q, i1 = j + 4 + q;          // < 64 always
            int   c0 = __shfl((int)e.x, i0);
            float v0 = __uint_as_float(__shfl((int)e.y, i0));
            int   c1 = __shfl((int)e.x, i1);
            float v1 = __uint_as_float(__shfl((int)e.y, i1));
            float4 x0 = *(const float4*)(x + (((size_t)c0) << 6) + (l16 << 2));
            float4 x1 = *(const float4*)(x + (((size_t)c1) << 6) + (l16 << 2));
            acc.x += v0 * x0.x; acc.y += v0 * x0.y;
            acc.z += v0 * x0.z; acc.w += v0 * x0.w;
            acc.x += v1 * x1.x; acc.y += v1 * x1.y;
            acc.z += v1 * x1.z; acc.w += v1 * x1.w;
        }
    }
    // reduce across the 4 edge-subgroups (lane bits 4,5)
    acc.x += __shfl_xor(acc.x, 16); acc.y += __shfl_xor(acc.y, 16);
    acc.z += __shfl_xor(acc.z, 16); acc.w += __shfl_xor(acc.w, 16);
    acc.x += __shfl_xor(acc.x, 32); acc.y += __shfl_xor(acc.y, 32);
    acc.z += __shfl_xor(acc.z, 32); acc.w += __shfl_xor(acc.w, 32);
    return acc;
}

// ---------------- C-even: per-row wave gather ----------------
__global__ __launch_bounds__(256) void row_gather(
        const int* __restrict__ offs, const uint2* __restrict__ edges,
        const float* __restrict__ x, float* __restrict__ out, int nrows) {
    int r = blockIdx.x * 4 + (threadIdx.x >> 6);
    int lane = threadIdx.x & 63;
    if (r >= nrows) return;
    float4 acc = gather_row4(offs[r], offs[r + 1], edges, x, lane);
    if ((lane >> 4) == 0)
        *(float4*)(out + (((size_t)r) << 6) + ((lane & 15) << 2)) = acc;
}

// ---------------- C-odd: XCD-partitioned gather into partials ---------------
__global__ __launch_bounds__(256) void xcd_gather(
        const int* __restrict__ offs, const uint2* __restrict__ edges,
        const float* __restrict__ x, float* __restrict__ partial, int NP) {
    int g = blockIdx.x;
    int slot = g & 7;
    int t = g >> 3;
    int wave = threadIdx.x >> 6, lane = threadIdx.x & 63;
    int r = t * 4 + wave;
    if (r >= NP) return;
    int bin = r * 8 + slot;
    float4 acc = gather_row4(offs[bin], offs[bin + 1], edges, x, lane);
    if ((lane >> 4) == 0)
        *(float4*)(partial + (size_t)slot * NP * 64 + (((size_t)r) << 6) + ((lane & 15) << 2)) = acc;
}

__global__ __launch_bounds__(256) void reduce8(
        const float* __restrict__ partial, float* __restrict__ out, int n4) {
    int i = blockIdx.x * 256 + threadIdx.x;
    if (i < n4) {
        const float4* p = (const float4*)partial;
        float4 s = make_float4(0.f, 0.f, 0.f, 0.f);
        #pragma unroll
        for (int xx = 0; xx < 8; ++xx) {
            float4 v = p[(size_t)xx * n4 + i];
            s.x += v.x; s.y += v.y; s.z += v.z; s.w += v.w;
        }
        ((float4*)out)[i] = s;
    }
}

// ---------------- fallback: round-1 atomic scatter ----------------
__global__ void spmm_scatter_kernel(const int* __restrict__ rows, const int* __restrict__ cols,
                                    const float* __restrict__ vals,
                                    const float* __restrict__ s_emb, const float* __restrict__ p_emb,
                                    float* __restrict__ out_s, float* __restrict__ out_p, int nnz) {
    long long t = (long long)blockIdx.x * blockDim.x + threadIdx.x;
    int e = (int)(t >> 6);
    int d = (int)(t & 63);
    if (e >= nnz) return;
    int r = rows[e];
    int c = cols[e];
    float v = vals[e];
    atomicAdd(&out_s[(size_t)r * 64 + d], v * p_emb[(size_t)c * 64 + d]);
    atomicAdd(&out_p[(size_t)c * 64 + d], v * s_emb[(size_t)r * 64 + d]);
}

// ---------------- host ----------------
extern "C" void kernel_launch(void* const* d_in, const int* in_sizes, int n_in,
                              void* d_out, int out_size, void* d_ws, size_t ws_size,
                              hipStream_t stream) {
    const float* s_emb   = (const float*)d_in[0];
    const float* p_emb   = (const float*)d_in[1];
    const int*   a_rows  = (const int*)d_in[2];
    const int*   a_cols  = (const int*)d_in[3];
    const float* a_vals  = (const float*)d_in[4];
    const int*   ia_rows = (const int*)d_in[5];
    const int*   ia_cols = (const int*)d_in[6];
    const float* ia_vals = (const float*)d_in[7];

    const int NS  = in_sizes[0] / 64;
    const int NP  = in_sizes[1] / 64;
    const int nnz = in_sizes[2];
    const int NP8 = NP * 8;

    float* out = (float*)d_out;
    float* out_sc  = out;
    float* out_sic = out_sc  + (size_t)NS * 64;
    float* out_pc  = out_sic + (size_t)NS * 64;
    float* out_pic = out_pc  + (size_t)NP * 64;

    int rsh_s = 0; while ((((long long)NS + (1LL << rsh_s) - 1) >> rsh_s) > NBMAX) rsh_s++;
    int rsh_p = 0; while ((((long long)NP + (1LL << rsh_p) - 1) >> rsh_p) > NBMAX) rsh_p++;
    int nb_s = (NS + (1 << rsh_s) - 1) >> rsh_s;
    int nb_p = (NP + (1 << rsh_p) - 1) >> rsh_p;
    unsigned mult8 = (unsigned)((8ULL << 32) / (unsigned)NS);

    const size_t edges_bytes = (size_t)nnz * sizeof(uint2);
    const size_t offsE_bytes = (size_t)(NS + 1) * sizeof(int);
    const size_t offsO_bytes = (size_t)(NP8 + 1) * sizeof(int);
    const size_t need = 2 * edges_bytes + offsE_bytes + offsO_bytes
                      + (size_t)(4 * NBMAX + 4 * (NBMAX + 1) + 4 * NBMAX) * sizeof(int) + 256;
    const bool packable = (NS <= 0xFFFF) && (NP <= 0xFFFF) &&
                          ((1 << rsh_s) <= BINSMAX) && ((8 << rsh_p) <= BINSMAX) &&
                          (edges_bytes >= (size_t)NP8 * 64 * sizeof(float)) &&
                          ((NP * 64) % 4 == 0);

    if (ws_size < need || !packable) {
        hipMemsetAsync(d_out, 0, (size_t)out_size * sizeof(float), stream);
        const long long total = (long long)nnz * 64;
        const int grid = (int)((total + 255) / 256);
        spmm_scatter_kernel<<<grid, 256, 0, stream>>>(a_rows, a_cols, a_vals, s_emb, p_emb,
                                                      out_sc, out_pc, nnz);
        spmm_scatter_kernel<<<grid, 256, 0, stream>>>(ia_rows, ia_cols, ia_vals, s_emb, p_emb,
                                                      out_sic, out_pic, nnz);
        return;
    }

    char* w = (char*)d_ws;
    uint2* edges1 = (uint2*)w;  w += edges_bytes;     // aliased as `partial` in odd gathers
    uint2* edges2 = (uint2*)w;  w += edges_bytes;
    int*   offsE  = (int*)w;    w += offsE_bytes;
    int*   offsO  = (int*)w;    w += offsO_bytes;
    int*   gcnt4  = (int*)w;    w += 4 * NBMAX * sizeof(int);
    int*   boffs4 = (int*)w;    w += 4 * (NBMAX + 1) * sizeof(int);
    int*   bcur4  = (int*)w;
    float* partial = (float*)edges1;

    hipMemsetAsync(gcnt4, 0, 4 * NBMAX * sizeof(int), stream);
    // dirs: 0 = a by row, 1 = a by col, 2 = ia by row, 3 = ia by col
    hist_all<<<1024, 256, 0, stream>>>(a_rows, a_cols, ia_rows, ia_cols,
                                       gcnt4, nnz, rsh_s, rsh_p);
    scan_all<<<4, 256, 0, stream>>>(gcnt4, boffs4, bcur4, nb_s, nb_p, nnz,
                                    offsE, offsO, NS, NP8);

    const int ntiles = (nnz + TILE - 1) / TILE;
    const int grid_rs_s = 64 * ((nb_s + 7) / 8);
    const int grid_rs_p = 64 * ((nb_p + 7) / 8);

    struct Dir { const int* key; const int* other; const float* vals;
                 float* out; int odd; };
    // output order: (student_c, student_ic, problem_c, problem_ic)
    Dir dirs[4] = {
        { a_rows,  a_cols,  a_vals,  out_sc,  0 },
        { a_cols,  a_rows,  a_vals,  out_pc,  1 },
        { ia_rows, ia_cols, ia_vals, out_sic, 0 },
        { ia_cols, ia_rows, ia_vals, out_pic, 1 },
    };
    for (int t = 0; t < 4; ++t) {
        const Dir& D = dirs[t];
        if (!D.odd) {
            staged_scatter<<<ntiles, 256, 0, stream>>>(D.key, D.other, D.vals,
                                                       bcur4 + t * NBMAX, edges1, nnz, rsh_s);
            row_scatter2<<<grid_rs_s, 512, 0, stream>>>(edges1, edges2,
                                                        boffs4 + t * (NBMAX + 1), offsE,
                                                        0, nb_s, rsh_s, NS, mult8);
            row_gather<<<(NS + 3) / 4, 256, 0, stream>>>(offsE, edges2, p_emb, D.out, NS);
        } else {
            staged_scatter<<<ntiles, 256, 0, stream>>>(D.key, D.other, D.vals,
                                                       bcur4 + t * NBMAX, edges1, nnz, rsh_p);
            row_scatter2<<<grid_rs_p, 512, 0, stream>>>(edges1, edges2,
                                                        boffs4 + t * (NBMAX + 1), offsO,
                                                        1, nb_p, rsh_p, NP, mult8);
            xcd_gather<<<8 * ((NP + 3) / 4), 256, 0, stream>>>(offsO, edges2,
                                                               s_emb, partial, NP);
            reduce8<<<(NP * 64 / 4 + 255) / 256, 256, 0, stream>>>(partial, D.out, NP * 64 / 4);
        }
    }
}